// Round 9
// baseline (21183.595 us; speedup 1.0000x reference)
//
#include <hip/hip_runtime.h>

#define B_ 64
#define TT 1024
#define HH 256
#define RING 8

__device__ __forceinline__ float sigmoidf_(float x) { return 1.f / (1.f + __expf(-x)); }
__device__ __forceinline__ float fast_tanh(float x) {
    float e = __expf(2.f * x);
    return 1.f - 2.f / (e + 1.f);
}
// Tagged-word exchange through LLC (agent scope). Tag occupies high 32 bits;
// poison 0xAAAAAAAA never equals a tag (tags < 1024), so no memset needed.
__device__ __forceinline__ float poll_word(const unsigned long long* p, unsigned tag) {
    unsigned long long v;
    do { v = __hip_atomic_load(p, __ATOMIC_RELAXED, __HIP_MEMORY_SCOPE_AGENT); }
    while ((unsigned)(v >> 32) != tag);
    return __uint_as_float((unsigned)v);
}
__device__ __forceinline__ void store_word(unsigned long long* p, unsigned tag, float v) {
    __hip_atomic_store(p, ((unsigned long long)tag << 32) | __float_as_uint(v),
                       __ATOMIC_RELAXED, __HIP_MEMORY_SCOPE_AGENT);
}

// ---------------------------------------------------------------------------
// Fused 2-layer LSTM, software-pipelined across layers.
// 512 WGs x 1024 thr: blocks [0,256) = layer-0 quads (b,q); [256,512) = layer-1.
// All co-resident: launch_bounds(1024,8) pins VGPR<=256 -> 2 WGs/CU, 512<=512.
// Thread map: w=tid>>6 (16 waves), l=tid&63; qc=l&3 (column quarter),
// rr=l>>2, gate=rr>>2, dimoff=rr&3; dim dl=4w+dimoff; gate row gr=gate*256+q*64+dl.
// 4 threads per gate row, 64/80 cols each; reduce shfl_xor(1,2); gather f/g/o
// via 3 all-lane shuffles; lanes {0,4,8,12} of each wave do the c/h update.
// Iter j: L0 computes h1[j] from (x[j], h1[j-1]); L1 computes h2[j] from
// (h1[j] polled from L0's concurrent iter, h2[j-1]). Serial chain = 1024 iters.
// L0 throttle: polls h2 tag j-7 so it can't overwrite ring slots (RING=8).
// ---------------------------------------------------------------------------
__global__ __launch_bounds__(1024, 8) void lstm_fused(
    const float* __restrict__ x,
    const float* __restrict__ Wih0, const float* __restrict__ Whh0,
    const float* __restrict__ bih0, const float* __restrict__ bhh0,
    const float* __restrict__ Wih1, const float* __restrict__ Whh1,
    const float* __restrict__ bih1, const float* __restrict__ bhh1,
    unsigned long long* __restrict__ h1r, unsigned long long* __restrict__ h2r)
{
    const int bid = (int)blockIdx.x;
    const bool isL0 = bid < 256;
    const int b = bid & 63;
    const int q = (bid >> 6) & 3;
    const int tid = (int)threadIdx.x;
    const int w = tid >> 6, l = tid & 63;
    const int qc = l & 3, rr = l >> 2;
    const int dimoff = rr & 3;
    const int dl = (w << 2) + dimoff;                  // local dim 0..63
    const int gr = ((rr >> 2) << 8) + (q << 6) + dl;   // global gate row

    __shared__ __align__(16) float bufA[2][4][68];     // h1 (quarters padded: banks 0,4,8,12)
    __shared__ __align__(16) float bufB[2][4][68];     // h2 (L1 only)
    __shared__ __align__(16) float xb[2][64];          // x  (L0 only)

    // Per-thread weights: L0 = 16 x-cols + 64 h1-cols; L1 = 64 h1 + 64 h2 cols.
    float4 wa[16], wb[16], wx[4];
    if (isL0) {
        const float4* p1 = (const float4*)(Wih0 + (size_t)gr * 64 + qc * 16);
#pragma unroll
        for (int i = 0; i < 4; ++i) wx[i] = p1[i];
        const float4* p2 = (const float4*)(Whh0 + (size_t)gr * 256 + qc * 64);
#pragma unroll
        for (int i = 0; i < 16; ++i) wa[i] = p2[i];
    } else {
        const float4* p1 = (const float4*)(Wih1 + (size_t)gr * 256 + qc * 64);
#pragma unroll
        for (int i = 0; i < 16; ++i) wa[i] = p1[i];
        const float4* p2 = (const float4*)(Whh1 + (size_t)gr * 256 + qc * 64);
#pragma unroll
        for (int i = 0; i < 16; ++i) wb[i] = p2[i];
    }
    float bias = 0.f;
    if (qc == 0)
        bias = isL0 ? (bih0[gr] + bhh0[gr]) : (bih1[gr] + bhh1[gr]);

    if (tid < 272) ((float*)bufA)[tid] = 0.f;                       // bufA[0] = h1[-1] = 0
    if (tid >= 512 && tid < 784) ((float*)bufB)[tid - 512] = 0.f;   // bufB[0] = h2[-1] = 0
    if (isL0 && tid < 64) xb[0][tid] = x[(size_t)b * 65536 + tid];  // x[0]
    float c = 0.f;
    unsigned long long* const myring = isL0 ? h1r : h2r;
    const size_t rbase = (size_t)b * (RING * 256);
    __syncthreads();

    for (int j = 0; j < TT; ++j) {
        const int cur = j & 1;

        // ---- gather this iter's inputs into buf[cur] (then barrier) ----
        if (isL0) {
            if (w < 4 && j >= 1)
                bufA[cur][w][l] = poll_word(
                    h1r + rbase + ((j - 1) & 7) * 256 + (w << 6) + l, j - 1);
        } else {
            if (w < 4)
                bufA[cur][w][l] = poll_word(
                    h1r + rbase + (j & 7) * 256 + (w << 6) + l, j);
            else if (w < 8 && j >= 1)
                bufB[cur][w - 4][l] = poll_word(
                    h2r + rbase + ((j - 1) & 7) * 256 + ((w - 4) << 6) + l, j - 1);
        }
        float xreg = 0.f;
        if (isL0 && w == 15) {
            if (j + 1 < TT)   // prefetch next x into registers (LDS write after barrier)
                xreg = x[(size_t)b * 65536 + (size_t)(j + 1) * 64 + l];
            if (j >= 7 && l == 0)   // ring-overwrite throttle: lag(L1) <= 7 < RING
                (void)poll_word(h2r + rbase + ((j - 7) & 7) * 256 + (q << 6), j - 7);
        }
        __syncthreads();
        if (isL0 && w == 15 && j + 1 < TT) xb[cur ^ 1][l] = xreg;

        // ---- GEMV: 4 threads/row, quarter qc, 4 independent accumulators ----
        float s0 = 0.f, s1 = 0.f, s2 = 0.f, s3 = 0.f;
        const float4* hA = (const float4*)&bufA[cur][qc][0];
        if (isL0) {
            const float4* xv = (const float4*)&xb[cur][qc * 16];
#pragma unroll
            for (int i = 0; i < 4; ++i) {
                float4 h = xv[i], v = wx[i];
                s0 = fmaf(v.x, h.x, s0); s1 = fmaf(v.y, h.y, s1);
                s2 = fmaf(v.z, h.z, s2); s3 = fmaf(v.w, h.w, s3);
            }
#pragma unroll
            for (int i = 0; i < 16; ++i) {
                float4 h = hA[i], v = wa[i];
                s0 = fmaf(v.x, h.x, s0); s1 = fmaf(v.y, h.y, s1);
                s2 = fmaf(v.z, h.z, s2); s3 = fmaf(v.w, h.w, s3);
            }
        } else {
            const float4* hB = (const float4*)&bufB[cur][qc][0];
#pragma unroll
            for (int i = 0; i < 16; ++i) {
                float4 h = hA[i], v = wa[i];
                s0 = fmaf(v.x, h.x, s0); s1 = fmaf(v.y, h.y, s1);
                s2 = fmaf(v.z, h.z, s2); s3 = fmaf(v.w, h.w, s3);
            }
#pragma unroll
            for (int i = 0; i < 16; ++i) {
                float4 h = hB[i], v = wb[i];
                s0 = fmaf(v.x, h.x, s0); s1 = fmaf(v.y, h.y, s1);
                s2 = fmaf(v.z, h.z, s2); s3 = fmaf(v.w, h.w, s3);
            }
        }
        float sum = (s0 + s1) + (s2 + s3) + bias;
        sum += __shfl_xor(sum, 1);   // combine the 4 column quarters
        sum += __shfl_xor(sum, 2);
        // Gather f/g/o rows of this dim — ALL 64 lanes execute the shuffles
        // (ds_bpermute reads from EXEC=0 source lanes return 0: round-7 lesson).
        float fv = __shfl(sum, ((4 + dimoff) << 2) | qc);
        float gv = __shfl(sum, ((8 + dimoff) << 2) | qc);
        float ov = __shfl(sum, ((12 + dimoff) << 2) | qc);

        if (rr < 4 && qc == 0) {   // lanes 0,4,8,12: own dims' gate update
            float i_ = sigmoidf_(sum);
            float f_ = sigmoidf_(fv);
            float g_ = fast_tanh(gv);
            float o_ = sigmoidf_(ov);
            c = fmaf(f_, c, i_ * g_);
            float hn = o_ * fast_tanh(c);
            store_word(myring + rbase + (j & 7) * 256 + (q << 6) + dl, j, hn);
        }
        // no end barrier: buf double-buffered; next iter's polls write buf[j^1]
    }
}

// ---------------------------------------------------------------------------
__global__ void fc_kernel(const unsigned long long* __restrict__ h2r,
                          const float* __restrict__ fcw, const float* __restrict__ fcb,
                          float* __restrict__ out)
{
    int b = threadIdx.x;
    if (b < 64) {
        const unsigned long long* h = h2r + ((size_t)b * RING + ((TT - 1) & 7)) * 256;
        float acc = 0.f;
        for (int d = 0; d < HH; ++d)
            acc = fmaf(__uint_as_float((unsigned)h[d]), fcw[d], acc);
        out[b] = acc + fcb[0];
    }
}

extern "C" void kernel_launch(void* const* d_in, const int* in_sizes, int n_in,
                              void* d_out, int out_size, void* d_ws, size_t ws_size,
                              hipStream_t stream)
{
    const float* x     = (const float*)d_in[0];   // [64][1024][64]
    const float* W_ih0 = (const float*)d_in[1];   // [1024][64]
    const float* W_hh0 = (const float*)d_in[2];   // [1024][256]
    const float* b_ih0 = (const float*)d_in[3];
    const float* b_hh0 = (const float*)d_in[4];
    const float* W_ih1 = (const float*)d_in[5];   // [1024][256]
    const float* W_hh1 = (const float*)d_in[6];   // [1024][256]
    const float* b_ih1 = (const float*)d_in[7];
    const float* b_hh1 = (const float*)d_in[8];
    const float* fc_w  = (const float*)d_in[9];   // [1][256]
    const float* fc_b  = (const float*)d_in[10];  // [1]
    float* out = (float*)d_out;

    // Workspace: two tagged-word rings, 1 MB each (tags self-validate vs 0xAA
    // poison -> no memset launch needed).
    unsigned long long* h1r = (unsigned long long*)d_ws;
    unsigned long long* h2r = h1r + (size_t)B_ * RING * 256;

    lstm_fused<<<dim3(512), dim3(1024), 0, stream>>>(
        x, W_ih0, W_hh0, b_ih0, b_hh0, W_ih1, W_hh1, b_ih1, b_hh1, h1r, h2r);

    fc_kernel<<<dim3(1), dim3(64), 0, stream>>>(h2r, fc_w, fc_b, out);
}

// Round 10
// 13790.961 us; speedup vs baseline: 1.5360x; 1.5360x over previous
//
#include <hip/hip_runtime.h>

#define B_ 64
#define TT 1024
#define HH 256

__device__ __forceinline__ float sigmoidf_(float x) { return 1.f / (1.f + __expf(-x)); }
__device__ __forceinline__ float fast_tanh(float x) {
    float e = __expf(2.f * x);
    return 1.f - 2.f / (e + 1.f);
}

// Tagged 8-byte word exchange. Fast path: sc0 store/load = write-through /
// read from the XCD-shared L2 (quads of one batch land on the same XCD under
// round-robin dispatch: bid = b + 64q, 64 = 0 mod 8). Guarantee path: a second
// store with sc0 sc1 (LLC) + a fallback agent load every 32 spins -- if the
// XCD assumption fails this degrades to the round-3 LLC protocol (no hang,
// no stale-value use: tag+value travel in one aligned 8B word).
__device__ __forceinline__ void store_word2(unsigned long long* p, unsigned tag, float v) {
    unsigned long long word = ((unsigned long long)tag << 32) | __float_as_uint(v);
    asm volatile("global_store_dwordx2 %0, %1, off sc0" :: "v"(p), "v"(word) : "memory");
    asm volatile("global_store_dwordx2 %0, %1, off sc0 sc1" :: "v"(p), "v"(word) : "memory");
}
__device__ __forceinline__ float poll_word2(unsigned long long* p, unsigned tag) {
    unsigned long long v;
    int spins = 0;
    for (;;) {
        asm volatile("global_load_dwordx2 %0, %1, off sc0\n\ts_waitcnt vmcnt(0)"
                     : "=v"(v) : "v"(p) : "memory");
        if ((unsigned)(v >> 32) == tag) break;
        if ((++spins & 31) == 0) {
            v = __hip_atomic_load(p, __ATOMIC_RELAXED, __HIP_MEMORY_SCOPE_AGENT);
            if ((unsigned)(v >> 32) == tag) break;
        }
        __builtin_amdgcn_s_sleep(1);
    }
    return __uint_as_float((unsigned)v);
}

// ---------------------------------------------------------------------------
// xgemm: out[M'][1024] = A'[M'][K] @ W[1024][K]^T + (bih+bhh)
// A' row m -> (b = m>>LC, tc = m&CM), element k at
//   A[((b*RINGA + slot)*K + k)*astr]   (astr=2 skips the tag lanes of hring).
// Tile 128x128, 256 threads, 8x8 outputs/thread.
// ---------------------------------------------------------------------------
__global__ __launch_bounds__(256) void xgemm_kernel(
    const float* __restrict__ A, const float* __restrict__ W,
    const float* __restrict__ bih, const float* __restrict__ bhh,
    float* __restrict__ out,
    int K, int RINGA, int s0A, int LC, int astr)
{
    __shared__ float As[16][132];
    __shared__ float Bs[16][132];
    const int tid = threadIdx.x;
    const int bm = (int)blockIdx.x >> 3;
    const int bn = (int)blockIdx.x & 7;
    const int m0 = bm << 7, n0 = bn << 7;
    const int ty = tid >> 4, tx = tid & 15;
    const int CM = (1 << LC) - 1;

    const float* arow[8];
    const float* brow[8];
#pragma unroll
    for (int i = 0; i < 8; ++i) {
        int mm = m0 + i * 16 + ty;
        int bb = mm >> LC, tc = mm & CM;
        int slot = s0A + tc; if (slot >= RINGA) slot -= RINGA;
        arow[i] = A + ((size_t)bb * RINGA + slot) * K * astr + tx * astr;
        brow[i] = W + (size_t)(n0 + i * 16 + ty) * K + tx;
    }

    float acc[8][8];
#pragma unroll
    for (int i = 0; i < 8; ++i)
#pragma unroll
        for (int j = 0; j < 8; ++j) acc[i][j] = 0.f;

    for (int kc = 0; kc < K; kc += 16) {
#pragma unroll
        for (int i = 0; i < 8; ++i) {
            As[tx][i * 16 + ty] = arow[i][kc * astr];
            Bs[tx][i * 16 + ty] = brow[i][kc];
        }
        __syncthreads();
#pragma unroll
        for (int k = 0; k < 16; ++k) {
            float a[8], bf[8];
#pragma unroll
            for (int j = 0; j < 8; ++j) a[j] = As[k][ty * 8 + j];
#pragma unroll
            for (int j = 0; j < 8; ++j) bf[j] = Bs[k][tx * 8 + j];
#pragma unroll
            for (int i = 0; i < 8; ++i)
#pragma unroll
                for (int j = 0; j < 8; ++j) acc[i][j] = fmaf(a[i], bf[j], acc[i][j]);
        }
        __syncthreads();
    }

    float bias[8];
#pragma unroll
    for (int j = 0; j < 8; ++j) bias[j] = bih[n0 + tx * 8 + j] + bhh[n0 + tx * 8 + j];
#pragma unroll
    for (int i = 0; i < 8; ++i) {
        float4 v0 = make_float4(acc[i][0] + bias[0], acc[i][1] + bias[1],
                                acc[i][2] + bias[2], acc[i][3] + bias[3]);
        float4 v1 = make_float4(acc[i][4] + bias[4], acc[i][5] + bias[5],
                                acc[i][6] + bias[6], acc[i][7] + bias[7]);
        size_t o = (size_t)(m0 + ty * 8 + i) * 1024 + n0 + tx * 8;
        *(float4*)&out[o] = v0;
        *(float4*)&out[o + 4] = v1;
    }
}

// ---------------------------------------------------------------------------
// Persistent-per-chunk recurrence -- EXACT round-3 structure (best measured:
// 408us/dispatch) + 4-accumulator GEMV + xg prefetch + L2-fast exchange.
// 256 WGs = 64 batch x 4 quads; WG owns 64 hidden dims (256 gate rows x 256
// cols of W_hh, 128 weight floats/thread, AGPR/VGPR-resident).
// Per step: all-wave GEMV -> shfl_xor(32) -> sh_gate -> barrier ->
// wave0: gates + sh_h + ring store | waves1-3: poll one peer slice each
// (concurrent with wave0's gate math) -> barrier.
// ---------------------------------------------------------------------------
__global__ __launch_bounds__(512) void recur_chunk(
    const float* __restrict__ xg,             // [B][CHUNK][1024]
    const float* __restrict__ Whh,            // [1024][256]
    unsigned long long* __restrict__ hring,   // [B][RING][256] (tag,val) words
    float* __restrict__ cstate,               // [256][64]
    int t0, int nsteps, int s0, int RING, int LC, int first)
{
    const int tid = threadIdx.x;
    const int b = (int)blockIdx.x & 63;
    const int q = (int)blockIdx.x >> 6;
    const int w = tid >> 6;          // wave 0..7
    const int l = tid & 63;
    const int hf = l >> 5;           // column half 0/1
    const int r = (w << 5) + (l & 31); // local gate row 0..255
    const int gr = ((r >> 6) << 8) + (q << 6) + (r & 63); // global gate row

    __shared__ __align__(16) float sh_h[256];
    __shared__ float sh_gate[256];

    // 128 weight floats per thread (resident in unified VGPR/AGPR file).
    float4 w4[32];
    {
        const float4* src = (const float4*)(Whh + (size_t)gr * 256 + (hf << 7));
#pragma unroll
        for (int j = 0; j < 32; ++j) w4[j] = src[j];
    }

    const size_t hbB = (size_t)b * RING;
    float c = 0.f;
    if (!first && tid < 64) c = cstate[((int)blockIdx.x << 6) + tid];
    if (tid < 256) {
        if (first) {
            sh_h[tid] = 0.f;
        } else {
            int sprev = (s0 == 0) ? RING - 1 : s0 - 1;
            unsigned long long v = hring[(hbB + sprev) * 256 + tid];
            sh_h[tid] = __uint_as_float((unsigned)v);
        }
    }
    __syncthreads();

    const float* xgp = xg + ((size_t)(b << LC) << 10) + gr;
    float xgv = (hf == 0) ? xgp[0] : 0.f;

    for (int tc = 0; tc < nsteps; ++tc) {
        const int t = t0 + tc;
        int slot = s0 + tc; if (slot >= RING) slot -= RING;
        const size_t srow = (hbB + slot) * 256;

        // Prefetch next step's xg value (latency hidden under the GEMV).
        float xgn = 0.f;
        if (hf == 0 && tc + 1 < nsteps) xgn = xgp[(size_t)(tc + 1) << 10];

        // GEMV: 4 independent accumulators (short dep chain).
        const float4* h4 = ((const float4*)sh_h) + (hf << 5);
        float a0 = 0.f, a1 = 0.f, a2 = 0.f, a3 = 0.f;
#pragma unroll
        for (int j = 0; j < 32; ++j) {
            float4 hv = h4[j], wv = w4[j];
            a0 = fmaf(wv.x, hv.x, a0); a1 = fmaf(wv.y, hv.y, a1);
            a2 = fmaf(wv.z, hv.z, a2); a3 = fmaf(wv.w, hv.w, a3);
        }
        float acc = (a0 + a1) + (a2 + a3);
        acc += __shfl_xor(acc, 32);           // combine column halves
        if (hf == 0) sh_gate[r] = acc + xgv;
        xgv = xgn;
        __syncthreads();

        if (tid < 64) {  // wave 0: gate update for our 64 hidden dims
            float gi = sh_gate[tid];
            float gf = sh_gate[64 + tid];
            float gg = sh_gate[128 + tid];
            float go = sh_gate[192 + tid];
            float i_ = sigmoidf_(gi);
            float f_ = sigmoidf_(gf);
            float g_ = fast_tanh(gg);
            float o_ = sigmoidf_(go);
            c = fmaf(f_, c, i_ * g_);
            float hn = o_ * fast_tanh(c);
            sh_h[(q << 6) + tid] = hn;
            store_word2(&hring[srow + (q << 6) + tid], (unsigned)t, hn);
        } else if (w <= 3) {  // waves 1..3: fetch one peer slice each
            const int p = (q + w) & 3;
            sh_h[(p << 6) + l] = poll_word2(&hring[srow + (p << 6) + l], (unsigned)t);
        }
        __syncthreads();
    }

    if (tid < 64) cstate[((int)blockIdx.x << 6) + tid] = c;
}

// ---------------------------------------------------------------------------
__global__ void fc_kernel(const unsigned long long* __restrict__ h2r,
                          int slot_last, int RING,
                          const float* __restrict__ fcw, const float* __restrict__ fcb,
                          float* __restrict__ out)
{
    int b = threadIdx.x;
    if (b < 64) {
        const unsigned long long* h = h2r + ((size_t)b * RING + slot_last) * 256;
        float acc = 0.f;
        for (int d = 0; d < HH; ++d)
            acc = fmaf(__uint_as_float((unsigned)h[d]), fcw[d], acc);
        out[b] = acc + fcb[0];
    }
}

extern "C" void kernel_launch(void* const* d_in, const int* in_sizes, int n_in,
                              void* d_out, int out_size, void* d_ws, size_t ws_size,
                              hipStream_t stream)
{
    const float* x     = (const float*)d_in[0];   // [64][1024][64]
    const float* W_ih0 = (const float*)d_in[1];   // [1024][64]
    const float* W_hh0 = (const float*)d_in[2];   // [1024][256]
    const float* b_ih0 = (const float*)d_in[3];
    const float* b_hh0 = (const float*)d_in[4];
    const float* W_ih1 = (const float*)d_in[5];   // [1024][256]
    const float* W_hh1 = (const float*)d_in[6];   // [1024][256]
    const float* b_ih1 = (const float*)d_in[7];
    const float* b_hh1 = (const float*)d_in[8];
    const float* fc_w  = (const float*)d_in[9];   // [1][256]
    const float* fc_b  = (const float*)d_in[10];  // [1]
    float* out = (float*)d_out;

    // Workspace-adaptive chunk size (deterministic across calls).
    auto need = [](size_t CH) -> size_t {
        return 4ull * (65536ull * CH            // xgc [64][CH][1024] f32
                     + 65536ull * (CH + 1)      // h1r+h2r rings, 8B words
                     + 32768ull);               // cstate x2
    };
    int CHUNK = 32, LC = 5;
    if      (ws_size >= need(256)) { CHUNK = 256; LC = 8; }
    else if (ws_size >= need(128)) { CHUNK = 128; LC = 7; }
    else if (ws_size >= need(64))  { CHUNK = 64;  LC = 6; }
    const int RING = CHUNK + 1;

    float* ws  = (float*)d_ws;
    float* xgc = ws;                                        // 65536*CHUNK f32
    unsigned long long* h1r =
        (unsigned long long*)(xgc + 65536ull * CHUNK);      // 16384*RING u64
    unsigned long long* h2r = h1r + 16384ull * RING;        // 16384*RING u64
    float* c0 = (float*)(h2r + 16384ull * RING);            // 16384 f32
    float* c1 = c0 + 16384;                                 // 16384 f32

    const int nchunks = TT / CHUNK;
    const int gemmblk = (B_ * CHUNK / 128) * 8;

    for (int k = 0; k < nchunks; ++k) {
        const int t0 = k * CHUNK;
        const int s0 = t0 % RING;
        const int first = (k == 0) ? 1 : 0;

        // Layer 0 input GEMM: A = x (plain f32, no ring, astr=1)
        xgemm_kernel<<<dim3(gemmblk), dim3(256), 0, stream>>>(
            x, W_ih0, b_ih0, b_hh0, xgc, 64, TT, t0, LC, 1);
        recur_chunk<<<dim3(256), dim3(512), 0, stream>>>(
            xgc, W_hh0, h1r, c0, t0, CHUNK, s0, RING, LC, first);

        // Layer 1 input GEMM: A = h1 ring (tagged pairs, astr=2)
        xgemm_kernel<<<dim3(gemmblk), dim3(256), 0, stream>>>(
            (const float*)h1r, W_ih1, b_ih1, b_hh1, xgc, 256, RING, s0, LC, 2);
        recur_chunk<<<dim3(256), dim3(512), 0, stream>>>(
            xgc, W_hh1, h2r, c1, t0, CHUNK, s0, RING, LC, first);
    }

    const int slot_last = (TT - 1) % RING;
    fc_kernel<<<dim3(1), dim3(64), 0, stream>>>(h2r, slot_last, RING, fc_w, fc_b, out);
}